// Round 5
// baseline (1008.487 us; speedup 1.0000x reference)
//
#include <hip/hip_runtime.h>
#include <math.h>
#include <limits.h>

#define DF 512
#define DH 64
#define DL 16
#define NC 10
#define NF 10
#define KPROP 10

#define BSH 7                  // bucket shift: 128 nodes per bucket
#define BW  (1 << BSH)
#define MAXB 1024
#define TILE 16384

typedef float __attribute__((ext_vector_type(2))) f2v;

__device__ __forceinline__ float softplus_(float x){
  return fmaxf(x, 0.0f) + log1pf(expf(-fabsf(x)));
}

// -------- GEMM1 fused with z-projection: z = relu(x@W1+b1) @ W2 + b2 --------
// 128x64 tile, 8x4 microtile, BK=32.
#define BM 128
#define BK 32
#define ATS 132                 // At row stride (multiple of 4, %32==4)
__global__ __launch_bounds__(256) void k_gemm1z(const float* __restrict__ x,
    const float* __restrict__ W1, const float* __restrict__ b1,
    const float* __restrict__ W2, const float* __restrict__ b2,
    float* __restrict__ z, int N)
{
  __shared__ float smem[BM*68];                 // 34.8KB: At|Bs during loop, hs after
  float (*At)[ATS] = (float(*)[ATS])smem;       // [32][132]
  float (*Bs)[68]  = (float(*)[68])(smem + BK*ATS);
  __shared__ float W2s[DH][DL];
  __shared__ float b2s[DL];
  const int tid = threadIdx.x;
  for (int i = tid; i < DH*DL; i += 256) W2s[i>>4][i&15] = W2[i];
  if (tid < DL) b2s[tid] = b2[tid];
  const int tx = tid & 15, ty = tid >> 4;       // 16 cols-groups x 16 row-groups
  const int row0 = blockIdx.x * BM;
  float acc[8][4] = {};
  for (int k0 = 0; k0 < DF; k0 += BK) {
    // stage x tile: 128 rows x 32 k = 1024 float4
    #pragma unroll
    for (int i = 0; i < 4; ++i) {
      int idx = tid + i*256;
      int r  = idx >> 3;                        // 0..127
      int kk = (idx & 7) << 2;                  // 0,4,...,28
      int row = row0 + r;
      float4 va = make_float4(0.f,0.f,0.f,0.f);
      if (row < N) va = *(const float4*)&x[(size_t)row*DF + k0 + kk];
      At[kk+0][r]=va.x; At[kk+1][r]=va.y; At[kk+2][r]=va.z; At[kk+3][r]=va.w;
    }
    // stage W1 tile: 32 x 64 = 512 float4
    #pragma unroll
    for (int i = 0; i < 2; ++i) {
      int idx = tid + i*256;
      int r2 = idx >> 4;                        // 0..31
      int c4 = (idx & 15) << 2;
      float4 vb = *(const float4*)&W1[(size_t)(k0+r2)*DH + c4];
      Bs[r2][c4+0]=vb.x; Bs[r2][c4+1]=vb.y; Bs[r2][c4+2]=vb.z; Bs[r2][c4+3]=vb.w;
    }
    __syncthreads();
    #pragma unroll
    for (int kk = 0; kk < BK; ++kk) {
      float4 a0 = *(const float4*)&At[kk][ty<<3];
      float4 a1 = *(const float4*)&At[kk][(ty<<3)+4];
      float4 bv = *(const float4*)&Bs[kk][tx<<2];
      float a8[8]={a0.x,a0.y,a0.z,a0.w,a1.x,a1.y,a1.z,a1.w};
      float b4[4]={bv.x,bv.y,bv.z,bv.w};
      #pragma unroll
      for (int i=0;i<8;++i)
        #pragma unroll
        for (int j=0;j<4;++j) acc[i][j] = fmaf(a8[i], b4[j], acc[i][j]);
    }
    __syncthreads();
  }
  // epilogue: h tile (128 x 64) -> LDS (overlay), then z = h@W2 + b2
  float4 bias = ((const float4*)b1)[tx];
  float bias4[4] = {bias.x, bias.y, bias.z, bias.w};
  float (*hs)[68] = (float(*)[68])smem;
  #pragma unroll
  for (int i=0;i<8;++i){
    float4 hv;
    hv.x = fmaxf(acc[i][0] + bias4[0], 0.f);
    hv.y = fmaxf(acc[i][1] + bias4[1], 0.f);
    hv.z = fmaxf(acc[i][2] + bias4[2], 0.f);
    hv.w = fmaxf(acc[i][3] + bias4[3], 0.f);
    *(float4*)&hs[(ty<<3)+i][tx<<2] = hv;
  }
  __syncthreads();
  int row = tid >> 1, lg = tid & 1;             // 128 rows x 2 half-z
  float4 z0 = ((const float4*)b2s)[lg*2];
  float4 z1 = ((const float4*)b2s)[lg*2+1];
  #pragma unroll 4
  for (int k4 = 0; k4 < DH/4; ++k4){
    float4 hv = *(const float4*)&hs[row][k4<<2];
    float hvv[4] = {hv.x, hv.y, hv.z, hv.w};
    #pragma unroll
    for (int kk = 0; kk < 4; ++kk){
      const float* wr = &W2s[(k4<<2)+kk][lg<<3];
      z0.x = fmaf(hvv[kk], wr[0], z0.x);
      z0.y = fmaf(hvv[kk], wr[1], z0.y);
      z0.z = fmaf(hvv[kk], wr[2], z0.z);
      z0.w = fmaf(hvv[kk], wr[3], z0.w);
      z1.x = fmaf(hvv[kk], wr[4], z1.x);
      z1.y = fmaf(hvv[kk], wr[5], z1.y);
      z1.z = fmaf(hvv[kk], wr[6], z1.z);
      z1.w = fmaf(hvv[kk], wr[7], z1.w);
    }
  }
  int grow = row0 + row;
  if (grow < N){
    ((float4*)z)[(size_t)grow*4 + lg*2    ] = z0;
    ((float4*)z)[(size_t)grow*4 + lg*2 + 1] = z1;
  }
}

// -------- radial flows: one thread per (node, class) --------
__global__ __launch_bounds__(256) void k_flow2(const float* __restrict__ z,
    const float* __restrict__ pc, const float* __restrict__ z0g,
    const float* __restrict__ apg, const float* __restrict__ fbg,
    float* __restrict__ x0, int N)
{
  __shared__ float z0s[NF][NC][DL];
  __shared__ float alps[NF][NC];
  __shared__ float bhs[NF][NC];
  __shared__ float lpc[NC];
  int tid = threadIdx.x;
  for (int i = tid; i < NF*NC*DL; i += 256)
    z0s[(i>>4)/NC][(i>>4)%NC][i&15] = z0g[i];
  if (tid < NF*NC){
    int l = tid/NC, c = tid%NC;
    float al = softplus_(apg[tid]);
    alps[l][c] = al;
    bhs[l][c]  = -al + softplus_(fbg[tid]);
  }
  if (tid < NC) lpc[tid] = __logf(pc[tid]);
  __syncthreads();

  int idx = blockIdx.x*256 + tid;
  int n = idx >> 4, c = idx & 15;
  if (n >= N) return;
  if (c >= NC){ x0[idx] = 0.f; return; }

  float zz[DL];
  const float4* z4 = (const float4*)z;
  #pragma unroll
  for (int q=0; q<4; ++q){
    float4 v = z4[(size_t)n*4 + q];
    zz[q*4+0]=v.x; zz[q*4+1]=v.y; zz[q*4+2]=v.z; zz[q*4+3]=v.w;
  }
  const float NEGHALFD_LOG2PI = -14.703016531274762f;  // -8*log(2*pi)
  const float LOGSCALE        =  20.248193975754326f;  //  8*log(4*pi)
  float sld = 0.f;
  #pragma unroll 1
  for (int l=0; l<NF; ++l){
    float al = alps[l][c], bhat = bhs[l][c];
    float dz[DL]; float r2 = 0.f;
    #pragma unroll
    for (int d=0; d<DL; ++d){ float t = zz[d] - z0s[l][c][d]; dz[d]=t; r2 = fmaf(t,t,r2); }
    float r  = sqrtf(r2);
    float hh = 1.0f/(al + r);
    float bh = bhat*hh;
    #pragma unroll
    for (int d=0; d<DL; ++d) zz[d] = fmaf(bh, dz[d], zz[d]);
    sld += 15.0f*__logf(1.0f + bh) + __logf(1.0f + bh - bhat*r*hh*hh);
  }
  float q2 = 0.f;
  #pragma unroll
  for (int d=0; d<DL; ++d) q2 = fmaf(zz[d], zz[d], q2);
  float v = -0.5f*q2 + NEGHALFD_LOG2PI + sld + lpc[c] + LOGSCALE;
  v = fminf(fmaxf(v, -30.f), 30.f);
  x0[idx] = __expf(v);
}

// ---------------- bucketed CSR construction ----------------
__global__ __launch_bounds__(256) void k_bhist(const int* __restrict__ dst,
    int* __restrict__ bCnt, int E, int B)
{
  __shared__ int hh[MAXB];
  int tid = threadIdx.x;
  for (int b = tid; b < B; b += 256) hh[b] = 0;
  __syncthreads();
  for (int i = blockIdx.x*256 + tid; i < E; i += gridDim.x*256)
    atomicAdd(&hh[dst[i] >> BSH], 1);
  __syncthreads();
  for (int b = tid; b < B; b += 256) if (hh[b]) atomicAdd(&bCnt[b], hh[b]);
}

__global__ void k_bscan(const int* __restrict__ bCnt, int* __restrict__ bOff, int B){
  if (blockIdx.x==0 && threadIdx.x==0){
    int run = 0;
    for (int b=0;b<B;++b){ bOff[b]=run; run+=bCnt[b]; }
    bOff[B]=run;
  }
}

__global__ __launch_bounds__(256) void k_bscatter(const int* __restrict__ src,
    const int* __restrict__ dst, const int* __restrict__ bOff,
    int* __restrict__ bCur, int* __restrict__ bp, int E, int B)
{
  __shared__ int hc[MAXB];
  __shared__ int hb[MAXB];
  int tid = threadIdx.x;
  int base = blockIdx.x * TILE;
  int lim  = base + TILE; if (lim > E) lim = E;
  for (int b = tid; b < B; b += 256) hc[b] = 0;
  __syncthreads();
  for (int i = base + tid; i < lim; i += 256)
    atomicAdd(&hc[dst[i] >> BSH], 1);
  __syncthreads();
  for (int b = tid; b < B; b += 256){
    int c = hc[b];
    hb[b] = c ? atomicAdd(&bCur[b], c) : 0;
    hc[b] = 0;
  }
  __syncthreads();
  for (int i = base + tid; i < lim; i += 256){
    int d = dst[i];
    int b = d >> BSH;
    int pos = bOff[b] + hb[b] + atomicAdd(&hc[b], 1);
    bp[pos] = (src[i] << BSH) | (d & (BW-1));
  }
}

// Pass B1: per-bucket in-degree count; +1 for the self loop
__global__ __launch_bounds__(256) void k_bdeg(const int* __restrict__ bp,
    const int* __restrict__ bOff, int* __restrict__ deg, int N)
{
  __shared__ int cur[BW];
  int tid = threadIdx.x;
  int b = blockIdx.x;
  if (tid < BW) cur[tid] = 0;
  __syncthreads();
  int s = bOff[b], e = bOff[b+1];
  for (int i = s + tid; i < e; i += 256)
    atomicAdd(&cur[bp[i] & (BW-1)], 1);
  __syncthreads();
  int node = (b << BSH) + tid;
  if (tid < BW && node < N) deg[node] = cur[tid] + 1;   // +1 self loop
}

__global__ void k_dinv(const int* __restrict__ deg, float* __restrict__ dinv, int N){
  int n = blockIdx.x*256 + threadIdx.x;
  if (n < N) dinv[n] = 1.0f / sqrtf((float)deg[n]);     // deg already includes self
}

__global__ __launch_bounds__(256) void k_scan_part(const int* __restrict__ deg,
    int* __restrict__ part, int N){
  __shared__ int sd[256];
  int base = blockIdx.x*1024;
  int tid = threadIdx.x;
  int s = 0;
  #pragma unroll
  for (int i=0;i<4;++i){ int idx = base + tid*4 + i; if (idx < N) s += deg[idx]; }
  sd[tid] = s; __syncthreads();
  for (int ofs=128; ofs>0; ofs>>=1){ if (tid<ofs) sd[tid]+=sd[tid+ofs]; __syncthreads(); }
  if (tid==0) part[blockIdx.x] = sd[0];
}

__global__ void k_scan_top(int* part, int nb){
  if (blockIdx.x==0 && threadIdx.x==0){
    int run = 0;
    for (int i=0;i<nb;++i){ int v = part[i]; part[i] = run; run += v; }
  }
}

__global__ __launch_bounds__(256) void k_scan_final(const int* __restrict__ deg,
    const int* __restrict__ part, int* __restrict__ off, int N, int E)
{
  __shared__ int sc[256];
  int base = blockIdx.x*1024;
  int tid = threadIdx.x;
  int v[4]; int s = 0;
  #pragma unroll
  for (int i=0;i<4;++i){ int idx = base + tid*4 + i; v[i] = (idx<N)?deg[idx]:0; s += v[i]; }
  sc[tid] = s; __syncthreads();
  for (int ofs=1; ofs<256; ofs<<=1){
    int t = (tid>=ofs) ? sc[tid-ofs] : 0;
    __syncthreads();
    sc[tid] += t;
    __syncthreads();
  }
  int ex = sc[tid] - s + part[blockIdx.x];
  #pragma unroll
  for (int i=0;i<4;++i){
    int idx = base + tid*4 + i;
    if (idx < N){
      off[idx] = ex;
      if (idx == N-1) off[N] = ex + v[i];
      ex += v[i];
    }
  }
}

// Pass B2: place self edge (slot 0) + (src, w) pairs at CSR positions
__global__ __launch_bounds__(256) void k_place(const int* __restrict__ bp,
    const int* __restrict__ bOff, const int* __restrict__ off,
    const float* __restrict__ dinv, float2* __restrict__ csrw, int N)
{
  __shared__ int cur[BW];
  int tid = threadIdx.x;
  int b = blockIdx.x;
  int node0 = b << BSH;
  if (tid < BW){
    cur[tid] = 1;                                 // slot 0 reserved for self
    int node = node0 + tid;
    if (node < N){
      float dn = dinv[node];
      csrw[off[node]] = make_float2(__int_as_float(node), dn*dn);
    }
  }
  __syncthreads();
  int s = bOff[b], e = bOff[b+1];
  for (int i = s + tid; i < e; i += 256){
    int v  = bp[i];
    int dl = v & (BW-1);
    int sn = v >> BSH;
    int d  = node0 + dl;
    int p  = off[d] + atomicAdd(&cur[dl], 1);
    csrw[p] = make_float2(__int_as_float(sn), dinv[sn]*dinv[d]);
  }
}

// ---- canonicalize segment order (stable value-rank via shuffles) ----
__global__ __launch_bounds__(256) void k_rank(float2* __restrict__ csrw,
    const int* __restrict__ off, int N)
{
  int wid  = (blockIdx.x*256 + threadIdx.x) >> 6;
  int lane = threadIdx.x & 63;
  if (wid >= N) return;
  int s = off[wid], e = off[wid+1];
  int d = e - s;
  if (d <= 1) return;
  if (d <= 64){
    float2 pv = (lane < d) ? csrw[s+lane] : make_float2(__int_as_float(INT_MAX), 0.f);
    int v = __float_as_int(pv.x);
    int rank = 0;
    for (int j = 0; j < d; ++j){
      int bv = __shfl(v, j);
      rank += (bv < v) || (bv == v && j < lane);
    }
    if (lane < d) csrw[s+rank] = pv;
  } else if (d <= 256){
    float2 p0 = (lane      < d) ? csrw[s+lane      ] : make_float2(__int_as_float(INT_MAX),0.f);
    float2 p1 = (lane+64   < d) ? csrw[s+lane+64   ] : make_float2(__int_as_float(INT_MAX),0.f);
    float2 p2 = (lane+128  < d) ? csrw[s+lane+128  ] : make_float2(__int_as_float(INT_MAX),0.f);
    float2 p3 = (lane+192  < d) ? csrw[s+lane+192  ] : make_float2(__int_as_float(INT_MAX),0.f);
    int v0=__float_as_int(p0.x), v1=__float_as_int(p1.x);
    int v2=__float_as_int(p2.x), v3=__float_as_int(p3.x);
    int r0=0,r1=0,r2=0,r3=0;
    for (int j = 0; j < d; ++j){
      int slot = j >> 6, jl = j & 63;
      int bv = (slot==0) ? __shfl(v0,jl) : (slot==1) ? __shfl(v1,jl)
             : (slot==2) ? __shfl(v2,jl) : __shfl(v3,jl);
      r0 += (bv < v0) || (bv == v0 && j < lane);
      r1 += (bv < v1) || (bv == v1 && j < lane+64);
      r2 += (bv < v2) || (bv == v2 && j < lane+128);
      r3 += (bv < v3) || (bv == v3 && j < lane+192);
    }
    if (lane      < d) csrw[s+r0]=p0;
    if (lane+64   < d) csrw[s+r1]=p1;
    if (lane+128  < d) csrw[s+r2]=p2;
    if (lane+192  < d) csrw[s+r3]=p3;
  } else {
    if (lane == 0){
      for (int i = s+1; i < e; ++i){
        float2 key = csrw[i];
        int kv = __float_as_int(key.x);
        int j = i-1;
        while (j >= s && __float_as_int(csrw[j].x) > kv){ csrw[j+1] = csrw[j]; --j; }
        csrw[j+1] = key;
      }
    }
  }
}

// ---------------- APPNP iteration: 4 threads/node, float4, unroll 4 ----------------
__global__ __launch_bounds__(256) void k_prop(const float* __restrict__ bsrc,
    const float* __restrict__ x0, float* __restrict__ bdst,
    const f2v* __restrict__ csrw, const int* __restrict__ off, int N)
{
  int t = blockIdx.x*256 + threadIdx.x;
  int n = t >> 2, q = t & 3;
  if (n >= N) return;
  const float4* b4 = (const float4*)bsrc;
  float4 a0 = make_float4(0.f,0.f,0.f,0.f);
  float4 a1 = make_float4(0.f,0.f,0.f,0.f);
  float4 a2 = make_float4(0.f,0.f,0.f,0.f);
  float4 a3 = make_float4(0.f,0.f,0.f,0.f);
  int s = off[n], e = off[n+1];
  int i = s;
  for (; i+4 <= e; i += 4){
    f2v p0 = __builtin_nontemporal_load(&csrw[i]);
    f2v p1 = __builtin_nontemporal_load(&csrw[i+1]);
    f2v p2 = __builtin_nontemporal_load(&csrw[i+2]);
    f2v p3 = __builtin_nontemporal_load(&csrw[i+3]);
    float4 v0 = b4[(size_t)__float_as_int(p0.x)*4 + q];
    float4 v1 = b4[(size_t)__float_as_int(p1.x)*4 + q];
    float4 v2 = b4[(size_t)__float_as_int(p2.x)*4 + q];
    float4 v3 = b4[(size_t)__float_as_int(p3.x)*4 + q];
    a0.x = fmaf(p0.y, v0.x, a0.x); a0.y = fmaf(p0.y, v0.y, a0.y);
    a0.z = fmaf(p0.y, v0.z, a0.z); a0.w = fmaf(p0.y, v0.w, a0.w);
    a1.x = fmaf(p1.y, v1.x, a1.x); a1.y = fmaf(p1.y, v1.y, a1.y);
    a1.z = fmaf(p1.y, v1.z, a1.z); a1.w = fmaf(p1.y, v1.w, a1.w);
    a2.x = fmaf(p2.y, v2.x, a2.x); a2.y = fmaf(p2.y, v2.y, a2.y);
    a2.z = fmaf(p2.y, v2.z, a2.z); a2.w = fmaf(p2.y, v2.w, a2.w);
    a3.x = fmaf(p3.y, v3.x, a3.x); a3.y = fmaf(p3.y, v3.y, a3.y);
    a3.z = fmaf(p3.y, v3.z, a3.z); a3.w = fmaf(p3.y, v3.w, a3.w);
  }
  for (; i < e; ++i){
    f2v p0 = __builtin_nontemporal_load(&csrw[i]);
    float4 v0 = b4[(size_t)__float_as_int(p0.x)*4 + q];
    a0.x = fmaf(p0.y, v0.x, a0.x); a0.y = fmaf(p0.y, v0.y, a0.y);
    a0.z = fmaf(p0.y, v0.z, a0.z); a0.w = fmaf(p0.y, v0.w, a0.w);
  }
  float4 xv = ((const float4*)x0)[(size_t)n*4 + q];
  float4 o;
  o.x = fmaf(0.9f, (a0.x+a1.x)+(a2.x+a3.x), 0.1f*xv.x);
  o.y = fmaf(0.9f, (a0.y+a1.y)+(a2.y+a3.y), 0.1f*xv.y);
  o.z = fmaf(0.9f, (a0.z+a1.z)+(a2.z+a3.z), 0.1f*xv.z);
  o.w = fmaf(0.9f, (a0.w+a1.w)+(a2.w+a3.w), 0.1f*xv.w);
  ((float4*)bdst)[(size_t)n*4 + q] = o;
}

// ---- last APPNP iteration fused with alpha/soft/argmax ----
__global__ __launch_bounds__(256) void k_prop_final(const float* __restrict__ bsrc,
    const float* __restrict__ x0,
    const f2v* __restrict__ csrw, const int* __restrict__ off,
    float* __restrict__ out, int N)
{
  int t = blockIdx.x*256 + threadIdx.x;
  int n = t >> 2, q = t & 3;
  if (n >= N) return;
  const float4* b4 = (const float4*)bsrc;
  float4 a0 = make_float4(0.f,0.f,0.f,0.f);
  float4 a1 = make_float4(0.f,0.f,0.f,0.f);
  float4 a2 = make_float4(0.f,0.f,0.f,0.f);
  float4 a3 = make_float4(0.f,0.f,0.f,0.f);
  int s = off[n], e = off[n+1];
  int i = s;
  for (; i+4 <= e; i += 4){
    f2v p0 = __builtin_nontemporal_load(&csrw[i]);
    f2v p1 = __builtin_nontemporal_load(&csrw[i+1]);
    f2v p2 = __builtin_nontemporal_load(&csrw[i+2]);
    f2v p3 = __builtin_nontemporal_load(&csrw[i+3]);
    float4 v0 = b4[(size_t)__float_as_int(p0.x)*4 + q];
    float4 v1 = b4[(size_t)__float_as_int(p1.x)*4 + q];
    float4 v2 = b4[(size_t)__float_as_int(p2.x)*4 + q];
    float4 v3 = b4[(size_t)__float_as_int(p3.x)*4 + q];
    a0.x = fmaf(p0.y, v0.x, a0.x); a0.y = fmaf(p0.y, v0.y, a0.y);
    a0.z = fmaf(p0.y, v0.z, a0.z); a0.w = fmaf(p0.y, v0.w, a0.w);
    a1.x = fmaf(p1.y, v1.x, a1.x); a1.y = fmaf(p1.y, v1.y, a1.y);
    a1.z = fmaf(p1.y, v1.z, a1.z); a1.w = fmaf(p1.y, v1.w, a1.w);
    a2.x = fmaf(p2.y, v2.x, a2.x); a2.y = fmaf(p2.y, v2.y, a2.y);
    a2.z = fmaf(p2.y, v2.z, a2.z); a2.w = fmaf(p2.y, v2.w, a2.w);
    a3.x = fmaf(p3.y, v3.x, a3.x); a3.y = fmaf(p3.y, v3.y, a3.y);
    a3.z = fmaf(p3.y, v3.z, a3.z); a3.w = fmaf(p3.y, v3.w, a3.w);
  }
  for (; i < e; ++i){
    f2v p0 = __builtin_nontemporal_load(&csrw[i]);
    float4 v0 = b4[(size_t)__float_as_int(p0.x)*4 + q];
    a0.x = fmaf(p0.y, v0.x, a0.x); a0.y = fmaf(p0.y, v0.y, a0.y);
    a0.z = fmaf(p0.y, v0.z, a0.z); a0.w = fmaf(p0.y, v0.w, a0.w);
  }
  float4 xv = ((const float4*)x0)[(size_t)n*4 + q];
  float4 al;
  al.x = fmaf(0.9f, (a0.x+a1.x)+(a2.x+a3.x), fmaf(0.1f, xv.x, 1.f));
  al.y = fmaf(0.9f, (a0.y+a1.y)+(a2.y+a3.y), fmaf(0.1f, xv.y, 1.f));
  al.z = fmaf(0.9f, (a0.z+a1.z)+(a2.z+a3.z), fmaf(0.1f, xv.z, 1.f));
  al.w = fmaf(0.9f, (a0.w+a1.w)+(a2.w+a3.w), fmaf(0.1f, xv.w, 1.f));

  float sv = 0.f;
  if (q < 2)       sv = al.x + al.y + al.z + al.w;
  else if (q == 2) sv = al.x + al.y;
  sv += __shfl_xor(sv, 1, 4);
  sv += __shfl_xor(sv, 2, 4);

  float bv = -1e30f; int bi = 999;
  int cb = q*4;
  int nvalid = (q < 2) ? 4 : (q == 2 ? 2 : 0);
  float av[4] = {al.x, al.y, al.z, al.w};
  for (int j = 0; j < nvalid; ++j){
    if (av[j] > bv){ bv = av[j]; bi = cb + j; }
  }
  #pragma unroll
  for (int o = 1; o <= 2; o <<= 1){
    float vo = __shfl_xor(bv, o, 4);
    int  io  = __shfl_xor(bi, o, 4);
    if (vo > bv || (vo == bv && io < bi)){ bv = vo; bi = io; }
  }

  float inv = 1.0f / sv;
  size_t sb = (size_t)N + (size_t)n*NC;
  for (int j = 0; j < nvalid; ++j) out[sb + cb + j] = av[j] * inv;
  if (q == 0) out[n] = (float)bi;
}

extern "C" void kernel_launch(void* const* d_in, const int* in_sizes, int n_in,
                              void* d_out, int out_size, void* d_ws, size_t ws_size,
                              hipStream_t stream)
{
  const float* x  = (const float*)d_in[0];
  const int*   ei = (const int*)  d_in[1];
  const float* pc = (const float*)d_in[2];
  const float* W1 = (const float*)d_in[3];
  const float* b1 = (const float*)d_in[4];
  const float* W2 = (const float*)d_in[5];
  const float* b2 = (const float*)d_in[6];
  const float* z0 = (const float*)d_in[7];
  const float* ap = (const float*)d_in[8];
  const float* fb = (const float*)d_in[9];
  float* out = (float*)d_out;

  const int N = in_sizes[0] / DF;
  const int E = in_sizes[1] / 2;
  const int* src = ei;
  const int* dst = ei + E;
  const int B = (N + BW - 1) >> BSH;

  // Workspace. region0 holds z (N*16 f32) during phase 1, then bp (E ints).
  char* ws = (char*)d_ws;
  size_t o = 0;
  size_t region0 = (size_t)N*DL*sizeof(float);
  if ((size_t)E*sizeof(int) > region0) region0 = (size_t)E*sizeof(int);
  float* z    = (float*)(ws + o);
  int*   bp   = (int*)  (ws + o);
  o += region0;
  float2* csrw = (float2*)(ws + o); o += (size_t)(E+N)*sizeof(float2);  // +N self edges
  float* x0   = (float*)(ws + o); o += (size_t)N*DL*sizeof(float);
  float* bA   = (float*)(ws + o); o += (size_t)N*DL*sizeof(float);
  float* bB   = (float*)(ws + o); o += (size_t)N*DL*sizeof(float);
  int*   deg  = (int*)  (ws + o); o += (size_t)N*sizeof(int);
  float* dinv = (float*)(ws + o); o += (size_t)N*sizeof(float);
  int*   offs = (int*)  (ws + o); o += (size_t)(N+2)*sizeof(int);
  int*   part = (int*)  (ws + o); o += 4096;
  int*   bCnt = (int*)  (ws + o); o += MAXB*sizeof(int);
  int*   bOff = (int*)  (ws + o); o += (MAXB+1)*sizeof(int);
  int*   bCur = (int*)  (ws + o); o += MAXB*sizeof(int);

  const int TB = 256;
  int gN  = (N + TB - 1) / TB;
  int nb  = (N + 1023) / 1024;

  // Phase 1: encoder fused with z projection, then flows -> x0
  k_gemm1z<<<(N + BM - 1) / BM, TB, 0, stream>>>(x, W1, b1, W2, b2, z, N);
  k_flow2<<<((N*DL) + TB - 1) / TB, TB, 0, stream>>>(z, pc, z0, ap, fb, x0, N);

  // Phase 2: bucketed CSR build (reuses z region for bp)
  hipMemsetAsync(bCnt, 0, MAXB*sizeof(int), stream);
  hipMemsetAsync(bCur, 0, MAXB*sizeof(int), stream);
  k_bhist<<<512, TB, 0, stream>>>(dst, bCnt, E, B);
  k_bscan<<<1, 1, 0, stream>>>(bCnt, bOff, B);
  k_bscatter<<<(E + TILE - 1)/TILE, TB, 0, stream>>>(src, dst, bOff, bCur, bp, E, B);
  k_bdeg<<<B, TB, 0, stream>>>(bp, bOff, deg, N);
  k_dinv<<<gN, TB, 0, stream>>>(deg, dinv, N);
  k_scan_part<<<nb, TB, 0, stream>>>(deg, part, N);
  k_scan_top<<<1, 1, 0, stream>>>(part, nb);
  k_scan_final<<<nb, TB, 0, stream>>>(deg, part, offs, N, E);
  k_place<<<B, TB, 0, stream>>>(bp, bOff, offs, dinv, csrw, N);
  k_rank<<<(N + 3) / 4, TB, 0, stream>>>(csrw, offs, N);

  // Phase 3: APPNP — 9 plain iterations + 1 fused with the epilogue
  int gP = ((N*4) + TB - 1) / TB;
  const float* bin = x0;
  for (int it = 0; it < KPROP-1; ++it){
    float* bout = (it & 1) ? bB : bA;
    k_prop<<<gP, TB, 0, stream>>>(bin, x0, bout, (const f2v*)csrw, offs, N);
    bin = bout;
  }
  k_prop_final<<<gP, TB, 0, stream>>>(bin, x0, (const f2v*)csrw, offs, out, N);
}

// Round 6
// 776.463 us; speedup vs baseline: 1.2988x; 1.2988x over previous
//
#include <hip/hip_runtime.h>
#include <math.h>
#include <limits.h>

#define DF 512
#define DH 64
#define DL 16
#define NC 10
#define NF 10
#define KPROP 10

#define BSH 7                  // bucket shift: 128 nodes per bucket
#define BW  (1 << BSH)
#define MAXB 1024
#define TILE 16384

__device__ __forceinline__ float softplus_(float x){
  return fmaxf(x, 0.0f) + log1pf(expf(-fabsf(x)));
}

// -------- GEMM1 fused with z-projection: z = relu(x@W1+b1) @ W2 + b2 --------
// (round-4 proven config: 64x64 tile, 4x4 microtile, BK=32)
#define BM 64
#define BN 64
#define BK 32
__global__ __launch_bounds__(256) void k_gemm1z(const float* __restrict__ x,
    const float* __restrict__ W1, const float* __restrict__ b1,
    const float* __restrict__ W2, const float* __restrict__ b2,
    float* __restrict__ z, int N)
{
  __shared__ float smem[2*BK*(BM+4)];           // At | Bs, later overlaid by hs[64][68]
  float (*At)[BM+4] = (float(*)[BM+4])smem;
  float (*Bs)[BN+4] = (float(*)[BN+4])(smem + BK*(BM+4));
  __shared__ float W2s[DH][DL];
  __shared__ float b2s[DL];
  const int tid = threadIdx.x;
  for (int i = tid; i < DH*DL; i += 256) W2s[i>>4][i&15] = W2[i];
  if (tid < DL) b2s[tid] = b2[tid];
  const int tx = tid & 15, ty = tid >> 4;
  const int row0 = blockIdx.x * BM;
  float acc[4][4] = {};
  for (int k0 = 0; k0 < DF; k0 += BK) {
    #pragma unroll
    for (int i = 0; i < 2; ++i) {
      int idx = tid + i*256;
      int r  = idx >> 3;
      int kk = (idx & 7) << 2;
      int row = row0 + r;
      float4 va = make_float4(0.f,0.f,0.f,0.f);
      if (row < N) va = *(const float4*)&x[(size_t)row*DF + k0 + kk];
      At[kk+0][r]=va.x; At[kk+1][r]=va.y; At[kk+2][r]=va.z; At[kk+3][r]=va.w;
      int r2 = idx >> 4;
      int c4 = (idx & 15) << 2;
      float4 vb = *(const float4*)&W1[(size_t)(k0+r2)*DH + c4];
      Bs[r2][c4+0]=vb.x; Bs[r2][c4+1]=vb.y; Bs[r2][c4+2]=vb.z; Bs[r2][c4+3]=vb.w;
    }
    __syncthreads();
    #pragma unroll
    for (int kk = 0; kk < BK; ++kk) {
      float4 av = *(const float4*)&At[kk][ty<<2];
      float4 bv = *(const float4*)&Bs[kk][tx<<2];
      float a4[4]={av.x,av.y,av.z,av.w};
      float b4[4]={bv.x,bv.y,bv.z,bv.w};
      #pragma unroll
      for (int i=0;i<4;++i)
        #pragma unroll
        for (int j=0;j<4;++j) acc[i][j] = fmaf(a4[i], b4[j], acc[i][j]);
    }
    __syncthreads();
  }
  // epilogue: h tile (64 rows x 64 hidden) -> LDS (overlay), then z = h@W2+b2
  float4 bias = ((const float4*)b1)[tx];
  float bias4[4] = {bias.x, bias.y, bias.z, bias.w};
  float (*hs)[BM+4] = (float(*)[BM+4])smem;
  #pragma unroll
  for (int i=0;i<4;++i){
    #pragma unroll
    for (int j=0;j<4;++j)
      hs[(ty<<2)+i][(tx<<2)+j] = fmaxf(acc[i][j] + bias4[j], 0.0f);
  }
  __syncthreads();
  int row = tid >> 2, lg = tid & 3;
  float4 zacc = ((const float4*)b2s)[lg];
  #pragma unroll 8
  for (int k = 0; k < DH; ++k){
    float hv = hs[row][k];
    float4 wv = *(const float4*)&W2s[k][lg<<2];
    zacc.x = fmaf(hv, wv.x, zacc.x);
    zacc.y = fmaf(hv, wv.y, zacc.y);
    zacc.z = fmaf(hv, wv.z, zacc.z);
    zacc.w = fmaf(hv, wv.w, zacc.w);
  }
  int grow = row0 + row;
  if (grow < N) ((float4*)z)[(size_t)grow*4 + lg] = zacc;
}

// -------- radial flows: one thread per (node, class) --------
// emits x0 (=beta_ft), c0 = dinv*x0, y0 = 0.1*dinv*x0
__global__ __launch_bounds__(256) void k_flow2(const float* __restrict__ z,
    const float* __restrict__ pc, const float* __restrict__ z0g,
    const float* __restrict__ apg, const float* __restrict__ fbg,
    const float* __restrict__ dinv,
    float* __restrict__ x0, float* __restrict__ c0, float* __restrict__ y0, int N)
{
  __shared__ float z0s[NF][NC][DL];
  __shared__ float alps[NF][NC];
  __shared__ float bhs[NF][NC];
  __shared__ float lpc[NC];
  int tid = threadIdx.x;
  for (int i = tid; i < NF*NC*DL; i += 256)
    z0s[(i>>4)/NC][(i>>4)%NC][i&15] = z0g[i];
  if (tid < NF*NC){
    int l = tid/NC, c = tid%NC;
    float al = softplus_(apg[tid]);
    alps[l][c] = al;
    bhs[l][c]  = -al + softplus_(fbg[tid]);
  }
  if (tid < NC) lpc[tid] = __logf(pc[tid]);
  __syncthreads();

  int idx = blockIdx.x*256 + tid;
  int n = idx >> 4, c = idx & 15;
  if (n >= N) return;
  float dn = dinv[n];
  if (c >= NC){ x0[idx] = 0.f; c0[idx] = 0.f; y0[idx] = 0.f; return; }

  float zz[DL];
  const float4* z4 = (const float4*)z;
  #pragma unroll
  for (int q=0; q<4; ++q){
    float4 v = z4[(size_t)n*4 + q];
    zz[q*4+0]=v.x; zz[q*4+1]=v.y; zz[q*4+2]=v.z; zz[q*4+3]=v.w;
  }
  const float NEGHALFD_LOG2PI = -14.703016531274762f;  // -8*log(2*pi)
  const float LOGSCALE        =  20.248193975754326f;  //  8*log(4*pi)
  float sld = 0.f;
  #pragma unroll 1
  for (int l=0; l<NF; ++l){
    float al = alps[l][c], bhat = bhs[l][c];
    float dz[DL]; float r2 = 0.f;
    #pragma unroll
    for (int d=0; d<DL; ++d){ float t = zz[d] - z0s[l][c][d]; dz[d]=t; r2 = fmaf(t,t,r2); }
    float r  = sqrtf(r2);
    float hh = 1.0f/(al + r);
    float bh = bhat*hh;
    #pragma unroll
    for (int d=0; d<DL; ++d) zz[d] = fmaf(bh, dz[d], zz[d]);
    sld += 15.0f*__logf(1.0f + bh) + __logf(1.0f + bh - bhat*r*hh*hh);
  }
  float q2 = 0.f;
  #pragma unroll
  for (int d=0; d<DL; ++d) q2 = fmaf(zz[d], zz[d], q2);
  float v = -0.5f*q2 + NEGHALFD_LOG2PI + sld + lpc[c] + LOGSCALE;
  v = fminf(fmaxf(v, -30.f), 30.f);
  float xv = __expf(v);
  x0[idx] = xv;
  c0[idx] = dn*xv;
  y0[idx] = 0.1f*dn*xv;
}

// ---------------- bucketed CSR construction ----------------
__global__ __launch_bounds__(256) void k_bhist(const int* __restrict__ dst,
    int* __restrict__ bCnt, int E, int B)
{
  __shared__ int hh[MAXB];
  int tid = threadIdx.x;
  for (int b = tid; b < B; b += 256) hh[b] = 0;
  __syncthreads();
  for (int i = blockIdx.x*256 + tid; i < E; i += gridDim.x*256)
    atomicAdd(&hh[dst[i] >> BSH], 1);
  __syncthreads();
  for (int b = tid; b < B; b += 256) if (hh[b]) atomicAdd(&bCnt[b], hh[b]);
}

__global__ void k_bscan(const int* __restrict__ bCnt, int* __restrict__ bOff, int B){
  if (blockIdx.x==0 && threadIdx.x==0){
    int run = 0;
    for (int b=0;b<B;++b){ bOff[b]=run; run+=bCnt[b]; }
    bOff[B]=run;
  }
}

__global__ __launch_bounds__(256) void k_bscatter(const int* __restrict__ src,
    const int* __restrict__ dst, const int* __restrict__ bOff,
    int* __restrict__ bCur, int* __restrict__ bp, int E, int B)
{
  __shared__ int hc[MAXB];
  __shared__ int hb[MAXB];
  int tid = threadIdx.x;
  int base = blockIdx.x * TILE;
  int lim  = base + TILE; if (lim > E) lim = E;
  for (int b = tid; b < B; b += 256) hc[b] = 0;
  __syncthreads();
  for (int i = base + tid; i < lim; i += 256)
    atomicAdd(&hc[dst[i] >> BSH], 1);
  __syncthreads();
  for (int b = tid; b < B; b += 256){
    int c = hc[b];
    hb[b] = c ? atomicAdd(&bCur[b], c) : 0;
    hc[b] = 0;
  }
  __syncthreads();
  for (int i = base + tid; i < lim; i += 256){
    int d = dst[i];
    int b = d >> BSH;
    int pos = bOff[b] + hb[b] + atomicAdd(&hc[b], 1);
    bp[pos] = (src[i] << BSH) | (d & (BW-1));
  }
}

// per-bucket in-degree count; +1 for the self loop
__global__ __launch_bounds__(256) void k_bdeg(const int* __restrict__ bp,
    const int* __restrict__ bOff, int* __restrict__ deg, int N)
{
  __shared__ int cur[BW];
  int tid = threadIdx.x;
  int b = blockIdx.x;
  if (tid < BW) cur[tid] = 0;
  __syncthreads();
  int s = bOff[b], e = bOff[b+1];
  for (int i = s + tid; i < e; i += 256)
    atomicAdd(&cur[bp[i] & (BW-1)], 1);
  __syncthreads();
  int node = (b << BSH) + tid;
  if (tid < BW && node < N) deg[node] = cur[tid] + 1;   // +1 self loop
}

__global__ void k_dinv(const int* __restrict__ deg, float* __restrict__ dinv,
    float* __restrict__ dinv2, int N){
  int n = blockIdx.x*256 + threadIdx.x;
  if (n < N){
    float d = (float)deg[n];
    float dv = 1.0f / sqrtf(d);
    dinv[n]  = dv;
    dinv2[n] = dv*dv;
  }
}

__global__ __launch_bounds__(256) void k_scan_part(const int* __restrict__ deg,
    int* __restrict__ part, int N){
  __shared__ int sd[256];
  int base = blockIdx.x*1024;
  int tid = threadIdx.x;
  int s = 0;
  #pragma unroll
  for (int i=0;i<4;++i){ int idx = base + tid*4 + i; if (idx < N) s += deg[idx]; }
  sd[tid] = s; __syncthreads();
  for (int ofs=128; ofs>0; ofs>>=1){ if (tid<ofs) sd[tid]+=sd[tid+ofs]; __syncthreads(); }
  if (tid==0) part[blockIdx.x] = sd[0];
}

__global__ void k_scan_top(int* part, int nb){
  if (blockIdx.x==0 && threadIdx.x==0){
    int run = 0;
    for (int i=0;i<nb;++i){ int v = part[i]; part[i] = run; run += v; }
  }
}

__global__ __launch_bounds__(256) void k_scan_final(const int* __restrict__ deg,
    const int* __restrict__ part, int* __restrict__ off, int N, int E)
{
  __shared__ int sc[256];
  int base = blockIdx.x*1024;
  int tid = threadIdx.x;
  int v[4]; int s = 0;
  #pragma unroll
  for (int i=0;i<4;++i){ int idx = base + tid*4 + i; v[i] = (idx<N)?deg[idx]:0; s += v[i]; }
  sc[tid] = s; __syncthreads();
  for (int ofs=1; ofs<256; ofs<<=1){
    int t = (tid>=ofs) ? sc[tid-ofs] : 0;
    __syncthreads();
    sc[tid] += t;
    __syncthreads();
  }
  int ex = sc[tid] - s + part[blockIdx.x];
  #pragma unroll
  for (int i=0;i<4;++i){
    int idx = base + tid*4 + i;
    if (idx < N){
      off[idx] = ex;
      if (idx == N-1) off[N] = ex + v[i];
      ex += v[i];
    }
  }
}

// place self edge (slot 0) + src ints at CSR positions
__global__ __launch_bounds__(256) void k_place(const int* __restrict__ bp,
    const int* __restrict__ bOff, const int* __restrict__ off,
    int* __restrict__ csr, int N)
{
  __shared__ int cur[BW];
  int tid = threadIdx.x;
  int b = blockIdx.x;
  int node0 = b << BSH;
  if (tid < BW){
    cur[tid] = 1;                                 // slot 0 reserved for self
    int node = node0 + tid;
    if (node < N) csr[off[node]] = node;
  }
  __syncthreads();
  int s = bOff[b], e = bOff[b+1];
  for (int i = s + tid; i < e; i += 256){
    int v  = bp[i];
    int dl = v & (BW-1);
    int sn = v >> BSH;
    int d  = node0 + dl;
    int p  = off[d] + atomicAdd(&cur[dl], 1);
    csr[p] = sn;
  }
}

// ---- canonicalize segment order (stable value-rank via shuffles) ----
__global__ __launch_bounds__(256) void k_rank(int* __restrict__ csr,
    const int* __restrict__ off, int N)
{
  int wid  = (blockIdx.x*256 + threadIdx.x) >> 6;
  int lane = threadIdx.x & 63;
  if (wid >= N) return;
  int s = off[wid], e = off[wid+1];
  int d = e - s;
  if (d <= 1) return;
  if (d <= 64){
    int v = (lane < d) ? csr[s+lane] : INT_MAX;
    int rank = 0;
    for (int j = 0; j < d; ++j){
      int bv = __shfl(v, j);
      rank += (bv < v) || (bv == v && j < lane);
    }
    if (lane < d) csr[s+rank] = v;
  } else if (d <= 256){
    int v0 = (lane      < d) ? csr[s+lane      ] : INT_MAX;
    int v1 = (lane+64   < d) ? csr[s+lane+64   ] : INT_MAX;
    int v2 = (lane+128  < d) ? csr[s+lane+128  ] : INT_MAX;
    int v3 = (lane+192  < d) ? csr[s+lane+192  ] : INT_MAX;
    int r0=0,r1=0,r2=0,r3=0;
    for (int j = 0; j < d; ++j){
      int slot = j >> 6, jl = j & 63;
      int bv = (slot==0) ? __shfl(v0,jl) : (slot==1) ? __shfl(v1,jl)
             : (slot==2) ? __shfl(v2,jl) : __shfl(v3,jl);
      r0 += (bv < v0) || (bv == v0 && j < lane);
      r1 += (bv < v1) || (bv == v1 && j < lane+64);
      r2 += (bv < v2) || (bv == v2 && j < lane+128);
      r3 += (bv < v3) || (bv == v3 && j < lane+192);
    }
    if (lane      < d) csr[s+r0]=v0;
    if (lane+64   < d) csr[s+r1]=v1;
    if (lane+128  < d) csr[s+r2]=v2;
    if (lane+192  < d) csr[s+r3]=v3;
  } else {
    if (lane == 0){
      for (int i = s+1; i < e; ++i){
        int key = csr[i]; int j = i-1;
        while (j >= s && csr[j] > key){ csr[j+1] = csr[j]; --j; }
        csr[j+1] = key;
      }
    }
  }
}

// ---- APPNP c-space iteration: c' = 0.9*dinv2*sum(c[src]) + y0 ----
__global__ __launch_bounds__(256) void k_prop(const float* __restrict__ cin,
    const float* __restrict__ y0, const float* __restrict__ dinv2,
    float* __restrict__ cout,
    const int* __restrict__ csr, const int* __restrict__ off, int N)
{
  int t = blockIdx.x*256 + threadIdx.x;
  int n = t >> 2, q = t & 3;
  if (n >= N) return;
  const float4* c4 = (const float4*)cin;
  float4 a0 = make_float4(0.f,0.f,0.f,0.f);
  float4 a1 = make_float4(0.f,0.f,0.f,0.f);
  float4 a2 = make_float4(0.f,0.f,0.f,0.f);
  float4 a3 = make_float4(0.f,0.f,0.f,0.f);
  int s = off[n], e = off[n+1];
  int i = s;
  for (; i+4 <= e; i += 4){
    int s0 = csr[i], s1 = csr[i+1], s2 = csr[i+2], s3 = csr[i+3];
    float4 v0 = c4[(size_t)s0*4 + q];
    float4 v1 = c4[(size_t)s1*4 + q];
    float4 v2 = c4[(size_t)s2*4 + q];
    float4 v3 = c4[(size_t)s3*4 + q];
    a0.x += v0.x; a0.y += v0.y; a0.z += v0.z; a0.w += v0.w;
    a1.x += v1.x; a1.y += v1.y; a1.z += v1.z; a1.w += v1.w;
    a2.x += v2.x; a2.y += v2.y; a2.z += v2.z; a2.w += v2.w;
    a3.x += v3.x; a3.y += v3.y; a3.z += v3.z; a3.w += v3.w;
  }
  for (; i < e; ++i){
    float4 v0 = c4[(size_t)csr[i]*4 + q];
    a0.x += v0.x; a0.y += v0.y; a0.z += v0.z; a0.w += v0.w;
  }
  float w9 = 0.9f * dinv2[n];
  float4 yv = ((const float4*)y0)[(size_t)n*4 + q];
  float4 o;
  o.x = fmaf(w9, (a0.x+a1.x)+(a2.x+a3.x), yv.x);
  o.y = fmaf(w9, (a0.y+a1.y)+(a2.y+a3.y), yv.y);
  o.z = fmaf(w9, (a0.z+a1.z)+(a2.z+a3.z), yv.z);
  o.w = fmaf(w9, (a0.w+a1.w)+(a2.w+a3.w), yv.w);
  ((float4*)cout)[(size_t)n*4 + q] = o;
}

// ---- last iteration fused with alpha/soft/argmax: beta = 0.9*dinv*sum + 0.1*x0 ----
__global__ __launch_bounds__(256) void k_prop_final(const float* __restrict__ cin,
    const float* __restrict__ x0, const float* __restrict__ dinv,
    const int* __restrict__ csr, const int* __restrict__ off,
    float* __restrict__ out, int N)
{
  int t = blockIdx.x*256 + threadIdx.x;
  int n = t >> 2, q = t & 3;
  if (n >= N) return;
  const float4* c4 = (const float4*)cin;
  float4 a0 = make_float4(0.f,0.f,0.f,0.f);
  float4 a1 = make_float4(0.f,0.f,0.f,0.f);
  float4 a2 = make_float4(0.f,0.f,0.f,0.f);
  float4 a3 = make_float4(0.f,0.f,0.f,0.f);
  int s = off[n], e = off[n+1];
  int i = s;
  for (; i+4 <= e; i += 4){
    int s0 = csr[i], s1 = csr[i+1], s2 = csr[i+2], s3 = csr[i+3];
    float4 v0 = c4[(size_t)s0*4 + q];
    float4 v1 = c4[(size_t)s1*4 + q];
    float4 v2 = c4[(size_t)s2*4 + q];
    float4 v3 = c4[(size_t)s3*4 + q];
    a0.x += v0.x; a0.y += v0.y; a0.z += v0.z; a0.w += v0.w;
    a1.x += v1.x; a1.y += v1.y; a1.z += v1.z; a1.w += v1.w;
    a2.x += v2.x; a2.y += v2.y; a2.z += v2.z; a2.w += v2.w;
    a3.x += v3.x; a3.y += v3.y; a3.z += v3.z; a3.w += v3.w;
  }
  for (; i < e; ++i){
    float4 v0 = c4[(size_t)csr[i]*4 + q];
    a0.x += v0.x; a0.y += v0.y; a0.z += v0.z; a0.w += v0.w;
  }
  float w9 = 0.9f * dinv[n];
  float4 xv = ((const float4*)x0)[(size_t)n*4 + q];
  float4 al;
  al.x = fmaf(w9, (a0.x+a1.x)+(a2.x+a3.x), fmaf(0.1f, xv.x, 1.f));
  al.y = fmaf(w9, (a0.y+a1.y)+(a2.y+a3.y), fmaf(0.1f, xv.y, 1.f));
  al.z = fmaf(w9, (a0.z+a1.z)+(a2.z+a3.z), fmaf(0.1f, xv.z, 1.f));
  al.w = fmaf(w9, (a0.w+a1.w)+(a2.w+a3.w), fmaf(0.1f, xv.w, 1.f));

  float sv = 0.f;
  if (q < 2)       sv = al.x + al.y + al.z + al.w;
  else if (q == 2) sv = al.x + al.y;
  sv += __shfl_xor(sv, 1, 4);
  sv += __shfl_xor(sv, 2, 4);

  float bv = -1e30f; int bi = 999;
  int cb = q*4;
  int nvalid = (q < 2) ? 4 : (q == 2 ? 2 : 0);
  float av[4] = {al.x, al.y, al.z, al.w};
  for (int j = 0; j < nvalid; ++j){
    if (av[j] > bv){ bv = av[j]; bi = cb + j; }
  }
  #pragma unroll
  for (int o = 1; o <= 2; o <<= 1){
    float vo = __shfl_xor(bv, o, 4);
    int  io  = __shfl_xor(bi, o, 4);
    if (vo > bv || (vo == bv && io < bi)){ bv = vo; bi = io; }
  }

  float inv = 1.0f / sv;
  size_t sb = (size_t)N + (size_t)n*NC;
  for (int j = 0; j < nvalid; ++j) out[sb + cb + j] = av[j] * inv;
  if (q == 0) out[n] = (float)bi;
}

extern "C" void kernel_launch(void* const* d_in, const int* in_sizes, int n_in,
                              void* d_out, int out_size, void* d_ws, size_t ws_size,
                              hipStream_t stream)
{
  const float* x  = (const float*)d_in[0];
  const int*   ei = (const int*)  d_in[1];
  const float* pc = (const float*)d_in[2];
  const float* W1 = (const float*)d_in[3];
  const float* b1 = (const float*)d_in[4];
  const float* W2 = (const float*)d_in[5];
  const float* b2 = (const float*)d_in[6];
  const float* z0 = (const float*)d_in[7];
  const float* ap = (const float*)d_in[8];
  const float* fb = (const float*)d_in[9];
  float* out = (float*)d_out;

  const int N = in_sizes[0] / DF;
  const int E = in_sizes[1] / 2;
  const int* src = ei;
  const int* dst = ei + E;
  const int B = (N + BW - 1) >> BSH;

  // Workspace. region0 holds bp (E ints) during CSR build, then z (N*16 f32)
  // for the encoder (bp is dead after k_place).
  char* ws = (char*)d_ws;
  size_t o = 0;
  size_t region0 = (size_t)E*sizeof(int);
  if ((size_t)N*DL*sizeof(float) > region0) region0 = (size_t)N*DL*sizeof(float);
  int*   bp   = (int*)  (ws + o);
  float* z    = (float*)(ws + o);
  o += region0;
  int*   csr  = (int*)  (ws + o); o += (size_t)(E+N)*sizeof(int);   // +N self edges
  float* x0   = (float*)(ws + o); o += (size_t)N*DL*sizeof(float);
  float* c0   = (float*)(ws + o); o += (size_t)N*DL*sizeof(float);
  float* y0   = (float*)(ws + o); o += (size_t)N*DL*sizeof(float);
  float* cA   = (float*)(ws + o); o += (size_t)N*DL*sizeof(float);
  float* cB   = (float*)(ws + o); o += (size_t)N*DL*sizeof(float);
  int*   deg  = (int*)  (ws + o); o += (size_t)N*sizeof(int);
  float* dinv = (float*)(ws + o); o += (size_t)N*sizeof(float);
  float* dinv2= (float*)(ws + o); o += (size_t)N*sizeof(float);
  int*   offs = (int*)  (ws + o); o += (size_t)(N+2)*sizeof(int);
  int*   part = (int*)  (ws + o); o += 4096;
  int*   bCnt = (int*)  (ws + o); o += MAXB*sizeof(int);
  int*   bOff = (int*)  (ws + o); o += (MAXB+1)*sizeof(int);
  int*   bCur = (int*)  (ws + o); o += MAXB*sizeof(int);

  const int TB = 256;
  int gN  = (N + TB - 1) / TB;
  int nb  = (N + 1023) / 1024;

  // Phase 1: bucketed CSR build (bp lives in region0)
  hipMemsetAsync(bCnt, 0, MAXB*sizeof(int), stream);
  hipMemsetAsync(bCur, 0, MAXB*sizeof(int), stream);
  k_bhist<<<512, TB, 0, stream>>>(dst, bCnt, E, B);
  k_bscan<<<1, 1, 0, stream>>>(bCnt, bOff, B);
  k_bscatter<<<(E + TILE - 1)/TILE, TB, 0, stream>>>(src, dst, bOff, bCur, bp, E, B);
  k_bdeg<<<B, TB, 0, stream>>>(bp, bOff, deg, N);
  k_dinv<<<gN, TB, 0, stream>>>(deg, dinv, dinv2, N);
  k_scan_part<<<nb, TB, 0, stream>>>(deg, part, N);
  k_scan_top<<<1, 1, 0, stream>>>(part, nb);
  k_scan_final<<<nb, TB, 0, stream>>>(deg, part, offs, N, E);
  k_place<<<B, TB, 0, stream>>>(bp, bOff, offs, csr, N);
  k_rank<<<(N + 3) / 4, TB, 0, stream>>>(csr, offs, N);

  // Phase 2: encoder fused with z projection (z overwrites bp), then flows
  k_gemm1z<<<(N + BM - 1) / BM, TB, 0, stream>>>(x, W1, b1, W2, b2, z, N);
  k_flow2<<<((N*DL) + TB - 1) / TB, TB, 0, stream>>>(z, pc, z0, ap, fb, dinv,
                                                     x0, c0, y0, N);

  // Phase 3: APPNP in c-space — 9 iterations + 1 fused with the epilogue
  int gP = ((N*4) + TB - 1) / TB;
  const float* cin = c0;
  for (int it = 0; it < KPROP-1; ++it){
    float* cout = (it & 1) ? cB : cA;
    k_prop<<<gP, TB, 0, stream>>>(cin, y0, dinv2, cout, csr, offs, N);
    cin = cout;
  }
  k_prop_final<<<gP, TB, 0, stream>>>(cin, x0, dinv, csr, offs, out, N);
}